// Round 1
// baseline (1746.672 us; speedup 1.0000x reference)
//
#include <hip/hip_runtime.h>

#define BATCH 8
#define LFRM  6
#define NP    2048
#define MP    1024
#define CIN   64
#define MIDC  128
#define OUTC  256
#define TKM   384
#define KNN   32
#define RAD2  0.25f

// ---------------------------------------------------------------------------
// Kernel 1: farthest-point sampling, one block per (b, frame). Bit-exact f32
// (fp contract OFF) so argmax indices match the reference exactly.
// Writes anchors (new_xyzs) straight into d_out.
// ---------------------------------------------------------------------------
__global__ __launch_bounds__(256) void fps_kernel(const float* __restrict__ xyzs,
                                                  float* __restrict__ out_xyz) {
#pragma clang fp contract(off)
  __shared__ float xs[NP], ys[NP], zs[NP];
  __shared__ int aidx[MP];
  __shared__ float rbv[4];
  __shared__ int rbi[4];
  __shared__ float fbx, fby, fbz;
  __shared__ int nfar;

  const int bt = blockIdx.x;                 // b*6 + frame
  const float* src = xyzs + (size_t)bt * NP * 3;
  const int tid = threadIdx.x;

  for (int q = tid; q < NP; q += 256) {
    xs[q] = src[q * 3 + 0];
    ys[q] = src[q * 3 + 1];
    zs[q] = src[q * 3 + 2];
  }
  __syncthreads();

  float dists[8];
#pragma unroll
  for (int u = 0; u < 8; ++u) dists[u] = 1e10f;

  int far = 0;
  float fx = xs[0], fy = ys[0], fz = zs[0];
  const int lane = tid & 63, wv = tid >> 6;

  for (int it = 0; it < MP; ++it) {
    if (tid == 0) aidx[it] = far;
    float bv = -1.0f;
    int bp = 0;
#pragma unroll
    for (int u = 0; u < 8; ++u) {
      int p = tid * 8 + u;
      float dx = xs[p] - fx, dy = ys[p] - fy, dz = zs[p] - fz;
      float d = dx * dx + dy * dy + dz * dz;   // contract off: matches ref
      float nd = fminf(dists[u], d);
      dists[u] = nd;
      if (nd > bv) { bv = nd; bp = p; }        // first-occurrence (u ascending)
    }
    // wave argmax reduce, first-occurrence tie-break (smaller index wins)
#pragma unroll
    for (int off = 32; off >= 1; off >>= 1) {
      float ov = __shfl_down(bv, off);
      int op = __shfl_down(bp, off);
      if (ov > bv || (ov == bv && op < bp)) { bv = ov; bp = op; }
    }
    if (lane == 0) { rbv[wv] = bv; rbi[wv] = bp; }
    __syncthreads();
    if (tid == 0) {
      float v = rbv[0];
      int p = rbi[0];
#pragma unroll
      for (int w = 1; w < 4; ++w)
        if (rbv[w] > v || (rbv[w] == v && rbi[w] < p)) { v = rbv[w]; p = rbi[w]; }
      nfar = p;
      fbx = xs[p]; fby = ys[p]; fbz = zs[p];
    }
    __syncthreads();
    far = nfar; fx = fbx; fy = fby; fz = fbz;
  }
  __syncthreads();

  float* dst = out_xyz + (size_t)bt * MP * 3;
  for (int m = tid; m < MP; m += 256) {
    int p = aidx[m];
    dst[m * 3 + 0] = xs[p];
    dst[m * 3 + 1] = ys[p];
    dst[m * 3 + 2] = zs[p];
  }
}

// ---------------------------------------------------------------------------
// Kernel 2: Ft[b,l,n,o] = sum_c w_f[o,c] * features[b,l,c,n]
// (grouping is a column gather, so transform once per point, not per (anchor,k))
// ---------------------------------------------------------------------------
__global__ __launch_bounds__(256) void ftrans_kernel(const float* __restrict__ features,
                                                     const float* __restrict__ w_f,
                                                     float* __restrict__ Ft) {
  __shared__ float ftile[CIN][64];        // [c][n]  16 KB
  __shared__ float wfT[CIN][MIDC + 1];    // [c][o]  padded: conflict-free writes

  const int blk = blockIdx.x;
  const int ntile = blk & 31;             // N/64 tiles
  const int bl = blk >> 5;                // b*L + l
  const int tid = threadIdx.x;

  const float* fsrc = features + (size_t)bl * CIN * NP + (size_t)ntile * 64;
  for (int idx = tid; idx < CIN * 64; idx += 256) {
    int c = idx >> 6, n = idx & 63;
    ftile[c][n] = fsrc[(size_t)c * NP + n];
  }
  for (int idx = tid; idx < CIN * MIDC; idx += 256) {
    int c = idx & 63, o = idx >> 6;       // coalesced w_f row reads
    wfT[c][o] = w_f[o * CIN + c];
  }
  __syncthreads();

  const int o = tid & 127, nh = tid >> 7;
  float* dst = Ft + ((size_t)bl * NP + (size_t)ntile * 64) * MIDC;
  for (int q = 0; q < 32; ++q) {
    int n = nh * 32 + q;
    float acc = 0.f;
#pragma unroll 16
    for (int c = 0; c < CIN; ++c) acc += wfT[c][o] * ftile[c][n];
    dst[(size_t)n * MIDC + o] = acc;
  }
}

// ---------------------------------------------------------------------------
// Kernel 3: ball query + max-pool mid + relu + fused w_t GEMM.
// One block per (b, t, 32-anchor tile). 256 threads:
//   ball query: wave per anchor (4 waves x 8 anchors sequential)
//   mid:        8 threads per anchor, 16 channels each (float4 Ft gathers)
//   w_t:        thread = out channel, 32 anchor accumulators in registers
// ---------------------------------------------------------------------------
__global__ __launch_bounds__(256) void pst_main(const float* __restrict__ xyzs,
                                                const float* __restrict__ w_d,
                                                const float* __restrict__ w_t,
                                                const float* __restrict__ Ft,
                                                const float* __restrict__ anchors,
                                                float* __restrict__ out_feat) {
  __shared__ float pxyz[NP * 3];          // 24 KB frame xyz (interleaved)
  __shared__ float sfp[32][MIDC];         // 16 KB one temporal slice of sf
  __shared__ int nidx[32][KNN];           // 4 KB
  __shared__ float anc[32][3];

  const int blk = blockIdx.x;
  const int mt = blk & 31;                // M/32 tiles
  const int bt = blk >> 5;                // b*6 + (t-1)
  const int b = bt / LFRM;
  const int t = bt % LFRM + 1;            // padded time index, 1..6
  const int tid = threadIdx.x;

  const float* asrc = anchors + ((size_t)bt * MP + (size_t)mt * 32) * 3;
  if (tid < 96) anc[tid / 3][tid % 3] = asrc[tid];
  __syncthreads();

  const int al = tid >> 3;                // anchor 0..31
  const int j = tid & 7;                  // 0..7 within anchor group
  const float ax = anc[al][0], ay = anc[al][1], az = anc[al][2];

  // preload this thread's 16 w_d rows: o = c4*32 + j*4 + r
  float wd[16][3];
#pragma unroll
  for (int c4 = 0; c4 < 4; ++c4)
#pragma unroll
    for (int r = 0; r < 4; ++r) {
      int o = c4 * 32 + j * 4 + r;
      wd[c4 * 4 + r][0] = w_d[o * 3 + 0];
      wd[c4 * 4 + r][1] = w_d[o * 3 + 1];
      wd[c4 * 4 + r][2] = w_d[o * 3 + 2];
    }

  const int lane = tid & 63, wv = tid >> 6;
  float acc2[32];
#pragma unroll
  for (int a = 0; a < 32; ++a) acc2[a] = 0.f;

  for (int ii = 0; ii < 3; ++ii) {
    const int i = t - 1 + ii;             // padded frame 0..7
    float acc[16];
    __syncthreads();                      // prev slice fully consumed

    if (i == 0 || i == LFRM + 1) {
      // zero-pad frame: grouped xyz/features are all zero regardless of the
      // ball query -> mid = -(w_d . anchor), identical over k.
#pragma unroll
      for (int u = 0; u < 16; ++u)
        acc[u] = -(wd[u][0] * ax + wd[u][1] * ay + wd[u][2] * az);
    } else {
      const int f2 = i - 1;
      const float* fxyz = xyzs + (size_t)(b * LFRM + f2) * NP * 3;
      for (int q = tid; q < NP * 3; q += 256) pxyz[q] = fxyz[q];
      __syncthreads();

      // ---- ball query: first KNN in-radius indices, in index order ----
      for (int aa = 0; aa < 8; ++aa) {
        const int a = wv * 8 + aa;
        const float qx = anc[a][0], qy = anc[a][1], qz = anc[a][2];
        int total = 0;
        int fillidx = 0;
        for (int ch = 0; ch < NP / 64; ++ch) {
          const int p = ch * 64 + lane;
          float d2;
          {
#pragma clang fp contract(off)
            float dx = qx - pxyz[p * 3 + 0];
            float dy = qy - pxyz[p * 3 + 1];
            float dz = qz - pxyz[p * 3 + 2];
            d2 = dx * dx + dy * dy + dz * dz;
          }
          const bool inb = d2 < RAD2;
          const unsigned long long mk = __ballot(inb);
          if (mk != 0ull && total == 0)
            fillidx = ch * 64 + (int)__builtin_ctzll(mk);
          const int before = (int)__builtin_popcountll(mk & ((1ull << lane) - 1ull));
          const int slot = total + before;
          if (inb && slot < KNN) nidx[a][slot] = p;
          total += (int)__builtin_popcountll(mk);
          if (total >= KNN) break;        // uniform across wave
        }
        const int nf = total < KNN ? total : KNN;
        if (lane < KNN - nf) nidx[a][nf + lane] = fillidx;
      }
      __syncthreads();

      // ---- mid: max over k of (Ft[idx_k] + w_d . disp_k) ----
      const float* ftf = Ft + (size_t)(b * LFRM + f2) * NP * MIDC;
#pragma unroll
      for (int u = 0; u < 16; ++u) acc[u] = -1e30f;
      for (int k = 0; k < KNN; ++k) {
        const int p = nidx[al][k];
        const float dx = pxyz[p * 3 + 0] - ax;
        const float dy = pxyz[p * 3 + 1] - ay;
        const float dz = pxyz[p * 3 + 2] - az;
        const float4* row = (const float4*)(ftf + (size_t)p * MIDC);
#pragma unroll
        for (int c4 = 0; c4 < 4; ++c4) {
          float4 v = row[c4 * 8 + j];
          const float* vf = (const float*)&v;
#pragma unroll
          for (int r = 0; r < 4; ++r) {
            float dt = wd[c4 * 4 + r][0] * dx + wd[c4 * 4 + r][1] * dy +
                       wd[c4 * 4 + r][2] * dz;
            acc[c4 * 4 + r] = fmaxf(acc[c4 * 4 + r], vf[r] + dt);
          }
        }
      }
    }

    // write relu'd slice to LDS
#pragma unroll
    for (int c4 = 0; c4 < 4; ++c4)
#pragma unroll
      for (int r = 0; r < 4; ++r) {
        int o = c4 * 32 + j * 4 + r;
        sfp[al][o] = fmaxf(acc[c4 * 4 + r], 0.f);
      }
    __syncthreads();

    // ---- fused w_t partial product for this temporal slice ----
    const float4* wrow = (const float4*)(w_t + (size_t)tid * TKM + (size_t)ii * MIDC);
    for (int c4 = 0; c4 < MIDC / 4; ++c4) {
      float4 w4 = wrow[c4];
#pragma unroll 8
      for (int a = 0; a < 32; ++a) {
        float4 s4 = *(const float4*)(&sfp[a][c4 * 4]);
        acc2[a] += w4.x * s4.x + w4.y * s4.y + w4.z * s4.z + w4.w * s4.w;
      }
    }
  }

  // out_feat[bt][o=tid][mt*32 + a]
  float* od = out_feat + ((size_t)bt * OUTC + tid) * MP + (size_t)mt * 32;
  float4* od4 = (float4*)od;
#pragma unroll
  for (int q = 0; q < 8; ++q)
    od4[q] = make_float4(acc2[q * 4 + 0], acc2[q * 4 + 1],
                         acc2[q * 4 + 2], acc2[q * 4 + 3]);
}

// ---------------------------------------------------------------------------
extern "C" void kernel_launch(void* const* d_in, const int* in_sizes, int n_in,
                              void* d_out, int out_size, void* d_ws, size_t ws_size,
                              hipStream_t stream) {
  const float* xyzs = (const float*)d_in[0];
  const float* features = (const float*)d_in[1];
  const float* w_d = (const float*)d_in[2];
  const float* w_f = (const float*)d_in[3];
  const float* w_t = (const float*)d_in[4];

  float* out = (float*)d_out;
  float* out_xyz = out;                                        // (B,6,M,3)
  float* out_feat = out + (size_t)BATCH * LFRM * MP * 3;       // (B,6,256,M)
  float* Ft = (float*)d_ws;                                    // (B,L,N,128) 50.3 MB

  hipLaunchKernelGGL(fps_kernel, dim3(BATCH * LFRM), dim3(256), 0, stream,
                     xyzs, out_xyz);
  hipLaunchKernelGGL(ftrans_kernel, dim3(BATCH * LFRM * (NP / 64)), dim3(256), 0,
                     stream, features, w_f, Ft);
  hipLaunchKernelGGL(pst_main, dim3(BATCH * LFRM * (MP / 32)), dim3(256), 0,
                     stream, xyzs, w_d, w_t, Ft, out_xyz, out_feat);
}

// Round 2
// 1321.579 us; speedup vs baseline: 1.3217x; 1.3217x over previous
//
#include <hip/hip_runtime.h>

#define BATCH 8
#define LFRM  6
#define NP    2048
#define MP    1024
#define CIN   64
#define MIDC  128
#define OUTC  256
#define TKM   384
#define KNN   32
#define RAD2  0.25f

#define FPS_BLOCKS (BATCH * LFRM)
#define FT_BLOCKS  (BATCH * LFRM * (NP / 64))

typedef float f2 __attribute__((ext_vector_type(2)));

// LDS union: fps path needs 32KB of interleaved points; ftrans needs 49.25KB.
union SharedU {
  float4 pts[NP];                      // fps: [x,y,z,pad] per point, 32 KB
  struct {
    float ftile[CIN][64];              // 16 KB
    float wfT[CIN][MIDC + 1];          // 33 KB
  } ft;
};

// ---- u64 argmax-key helpers: key = (f32_bits(value) << 32) | ~index --------
// max(key) == (max value, min index) == numpy first-occurrence argmax.
__device__ __forceinline__ uint64_t kmax64(uint64_t a, uint64_t b) {
  return a > b ? a : b;                // v_cmp_lt_u64 + 2 cndmask
}
template <int CTRL>
__device__ __forceinline__ uint64_t key_dpp(uint64_t k) {
  int lo = __builtin_amdgcn_update_dpp((int)(uint32_t)k, (int)(uint32_t)k,
                                       CTRL, 0xF, 0xF, false);
  int hi = __builtin_amdgcn_update_dpp((int)(uint32_t)(k >> 32),
                                       (int)(uint32_t)(k >> 32),
                                       CTRL, 0xF, 0xF, false);
  return ((uint64_t)(uint32_t)hi << 32) | (uint32_t)lo;
}
__device__ __forceinline__ uint64_t key_swz16(uint64_t k) {
  int lo = __builtin_amdgcn_ds_swizzle((int)(uint32_t)k, 0x401F);  // xor 16
  int hi = __builtin_amdgcn_ds_swizzle((int)(uint32_t)(k >> 32), 0x401F);
  return ((uint64_t)(uint32_t)hi << 32) | (uint32_t)lo;
}
__device__ __forceinline__ uint64_t key_x32(uint64_t k) {
  int lo = __shfl_xor((int)(uint32_t)k, 32);
  int hi = __shfl_xor((int)(uint32_t)(k >> 32), 32);
  return ((uint64_t)(uint32_t)hi << 32) | (uint32_t)lo;
}

// ---------------------------------------------------------------------------
// FPS: single wave, all 2048 points register-resident as float2 pairs.
// Point p = slot*64 + lane; pair u holds slots {2u, 2u+1}. No barriers.
// ---------------------------------------------------------------------------
__device__ __forceinline__ void fps_path(const float* __restrict__ xyzs,
                                         float* __restrict__ out_xyz,
                                         SharedU* sh) {
#pragma clang fp contract(off)
  const int bt = blockIdx.x;              // b*6 + frame
  const int lane = threadIdx.x;           // 0..63
  const float* src = xyzs + (size_t)bt * NP * 3;

  // stage interleaved float4 copy (also serves the winner-coords broadcast)
  for (int q = lane; q < NP; q += 64)
    sh->pts[q] = make_float4(src[q * 3 + 0], src[q * 3 + 1], src[q * 3 + 2], 0.f);
  // single wave: DS ops are processed in wave order; wait for writes to land
  asm volatile("s_waitcnt lgkmcnt(0)" ::: "memory");

  f2 px[16], py[16], pz[16], dist[16];
#pragma unroll
  for (int u = 0; u < 16; ++u) {
    float4 a = sh->pts[(2 * u) * 64 + lane];
    float4 b = sh->pts[(2 * u + 1) * 64 + lane];
    px[u] = f2{a.x, b.x};
    py[u] = f2{a.y, b.y};
    pz[u] = f2{a.z, b.z};
    dist[u] = f2{1e10f, 1e10f};
  }

  float4 p0 = sh->pts[0];
  float fx = p0.x, fy = p0.y, fz = p0.z;  // far = 0 initially
  float* dst = out_xyz + (size_t)bt * MP * 3;

  for (int it = 0; it < MP; ++it) {
    if (lane == 0) {                      // emit current far point
      dst[it * 3 + 0] = fx;
      dst[it * 3 + 1] = fy;
      dst[it * 3 + 2] = fz;
    }
    const f2 fx2 = {fx, fx}, fy2 = {fy, fy}, fz2 = {fz, fz};
    float bv = -1.0f;
    int bs = 0;
#pragma unroll
    for (int u = 0; u < 16; ++u) {
      f2 dx = px[u] - fx2;                // v_pk_add (neg)
      f2 dy = py[u] - fy2;
      f2 dz = pz[u] - fz2;
      f2 m = dx * dx;                     // contract off: ((dx^2+dy^2)+dz^2)
      m = m + dy * dy;
      m = m + dz * dz;
      f2 nd = __builtin_elementwise_min(dist[u], m);
      dist[u] = nd;
      bool cx = nd.x > bv;                // first-occurrence: strict >
      bv = cx ? nd.x : bv;
      bs = cx ? 2 * u : bs;
      bool cy = nd.y > bv;
      bv = cy ? nd.y : bv;
      bs = cy ? 2 * u + 1 : bs;
    }
    const uint32_t p = ((uint32_t)bs << 6) | (uint32_t)lane;
    uint64_t key = ((uint64_t)__float_as_uint(bv) << 32) | (uint32_t)(~p);
    key = kmax64(key, key_dpp<0x121>(key));   // row_ror:1
    key = kmax64(key, key_dpp<0x122>(key));   // row_ror:2
    key = kmax64(key, key_dpp<0x124>(key));   // row_ror:4
    key = kmax64(key, key_dpp<0x128>(key));   // row_ror:8
    key = kmax64(key, key_swz16(key));        // lane ^ 16
    key = kmax64(key, key_x32(key));          // lane ^ 32
    const uint32_t wp = ~(uint32_t)key;       // winner point index
    float4 w = sh->pts[wp];                   // uniform addr -> broadcast read
    fx = w.x; fy = w.y; fz = w.z;
  }
}

// ---------------------------------------------------------------------------
// ftrans: Ft[b,l,n,o] = sum_c w_f[o,c] * features[b,l,c,n]
// ---------------------------------------------------------------------------
__device__ __forceinline__ void ftrans_path(const float* __restrict__ features,
                                            const float* __restrict__ w_f,
                                            float* __restrict__ Ft,
                                            SharedU* sh) {
  const int blk = blockIdx.x - FPS_BLOCKS;
  const int ntile = blk & 31;             // N/64 tiles
  const int bl = blk >> 5;                // b*L + l
  const int tid = threadIdx.x;

  const float* fsrc = features + (size_t)bl * CIN * NP + (size_t)ntile * 64;
  for (int idx = tid; idx < CIN * 64; idx += 256) {
    int c = idx >> 6, n = idx & 63;
    sh->ft.ftile[c][n] = fsrc[(size_t)c * NP + n];
  }
  for (int idx = tid; idx < CIN * MIDC; idx += 256) {
    int c = idx & 63, o = idx >> 6;       // coalesced w_f row reads
    sh->ft.wfT[c][o] = w_f[o * CIN + c];
  }
  __syncthreads();

  const int o = tid & 127, nh = tid >> 7;
  float* dst = Ft + ((size_t)bl * NP + (size_t)ntile * 64) * MIDC;
  for (int q = 0; q < 32; ++q) {
    int n = nh * 32 + q;
    float acc = 0.f;
#pragma unroll 16
    for (int c = 0; c < CIN; ++c) acc += sh->ft.wfT[c][o] * sh->ft.ftile[c][n];
    dst[(size_t)n * MIDC + o] = acc;
  }
}

__global__ __launch_bounds__(256, 1) void fps_ftrans_kernel(
    const float* __restrict__ xyzs, const float* __restrict__ features,
    const float* __restrict__ w_f, float* __restrict__ out_xyz,
    float* __restrict__ Ft) {
  __shared__ SharedU sh;
  if (blockIdx.x < FPS_BLOCKS) {
    if (threadIdx.x < 64) fps_path(xyzs, out_xyz, &sh);
    return;
  }
  ftrans_path(features, w_f, Ft, &sh);
}

// ---------------------------------------------------------------------------
// Kernel 3: ball query + max-pool mid + relu + fused w_t GEMM (unchanged).
// ---------------------------------------------------------------------------
__global__ __launch_bounds__(256) void pst_main(const float* __restrict__ xyzs,
                                                const float* __restrict__ w_d,
                                                const float* __restrict__ w_t,
                                                const float* __restrict__ Ft,
                                                const float* __restrict__ anchors,
                                                float* __restrict__ out_feat) {
  __shared__ float pxyz[NP * 3];          // 24 KB frame xyz (interleaved)
  __shared__ float sfp[32][MIDC];         // 16 KB one temporal slice of sf
  __shared__ int nidx[32][KNN];           // 4 KB
  __shared__ float anc[32][3];

  const int blk = blockIdx.x;
  const int mt = blk & 31;                // M/32 tiles
  const int bt = blk >> 5;                // b*6 + (t-1)
  const int b = bt / LFRM;
  const int t = bt % LFRM + 1;            // padded time index, 1..6
  const int tid = threadIdx.x;

  const float* asrc = anchors + ((size_t)bt * MP + (size_t)mt * 32) * 3;
  if (tid < 96) anc[tid / 3][tid % 3] = asrc[tid];
  __syncthreads();

  const int al = tid >> 3;                // anchor 0..31
  const int j = tid & 7;                  // 0..7 within anchor group
  const float ax = anc[al][0], ay = anc[al][1], az = anc[al][2];

  float wd[16][3];
#pragma unroll
  for (int c4 = 0; c4 < 4; ++c4)
#pragma unroll
    for (int r = 0; r < 4; ++r) {
      int o = c4 * 32 + j * 4 + r;
      wd[c4 * 4 + r][0] = w_d[o * 3 + 0];
      wd[c4 * 4 + r][1] = w_d[o * 3 + 1];
      wd[c4 * 4 + r][2] = w_d[o * 3 + 2];
    }

  const int lane = tid & 63, wv = tid >> 6;
  float acc2[32];
#pragma unroll
  for (int a = 0; a < 32; ++a) acc2[a] = 0.f;

  for (int ii = 0; ii < 3; ++ii) {
    const int i = t - 1 + ii;             // padded frame 0..7
    float acc[16];
    __syncthreads();                      // prev slice fully consumed

    if (i == 0 || i == LFRM + 1) {
#pragma unroll
      for (int u = 0; u < 16; ++u)
        acc[u] = -(wd[u][0] * ax + wd[u][1] * ay + wd[u][2] * az);
    } else {
      const int f2i = i - 1;
      const float* fxyz = xyzs + (size_t)(b * LFRM + f2i) * NP * 3;
      for (int q = tid; q < NP * 3; q += 256) pxyz[q] = fxyz[q];
      __syncthreads();

      // ---- ball query: first KNN in-radius indices, in index order ----
      for (int aa = 0; aa < 8; ++aa) {
        const int a = wv * 8 + aa;
        const float qx = anc[a][0], qy = anc[a][1], qz = anc[a][2];
        int total = 0;
        int fillidx = 0;
        for (int ch = 0; ch < NP / 64; ++ch) {
          const int p = ch * 64 + lane;
          float d2;
          {
#pragma clang fp contract(off)
            float dx = qx - pxyz[p * 3 + 0];
            float dy = qy - pxyz[p * 3 + 1];
            float dz = qz - pxyz[p * 3 + 2];
            d2 = dx * dx + dy * dy + dz * dz;
          }
          const bool inb = d2 < RAD2;
          const unsigned long long mk = __ballot(inb);
          if (mk != 0ull && total == 0)
            fillidx = ch * 64 + (int)__builtin_ctzll(mk);
          const int before = (int)__builtin_popcountll(mk & ((1ull << lane) - 1ull));
          const int slot = total + before;
          if (inb && slot < KNN) nidx[a][slot] = p;
          total += (int)__builtin_popcountll(mk);
          if (total >= KNN) break;        // uniform across wave
        }
        const int nf = total < KNN ? total : KNN;
        if (lane < KNN - nf) nidx[a][nf + lane] = fillidx;
      }
      __syncthreads();

      // ---- mid: max over k of (Ft[idx_k] + w_d . disp_k) ----
      const float* ftf = Ft + (size_t)(b * LFRM + f2i) * NP * MIDC;
#pragma unroll
      for (int u = 0; u < 16; ++u) acc[u] = -1e30f;
      for (int k = 0; k < KNN; ++k) {
        const int p = nidx[al][k];
        const float dx = pxyz[p * 3 + 0] - ax;
        const float dy = pxyz[p * 3 + 1] - ay;
        const float dz = pxyz[p * 3 + 2] - az;
        const float4* row = (const float4*)(ftf + (size_t)p * MIDC);
#pragma unroll
        for (int c4 = 0; c4 < 4; ++c4) {
          float4 v = row[c4 * 8 + j];
          const float* vf = (const float*)&v;
#pragma unroll
          for (int r = 0; r < 4; ++r) {
            float dt = wd[c4 * 4 + r][0] * dx + wd[c4 * 4 + r][1] * dy +
                       wd[c4 * 4 + r][2] * dz;
            acc[c4 * 4 + r] = fmaxf(acc[c4 * 4 + r], vf[r] + dt);
          }
        }
      }
    }

    // write relu'd slice to LDS
#pragma unroll
    for (int c4 = 0; c4 < 4; ++c4)
#pragma unroll
      for (int r = 0; r < 4; ++r) {
        int o = c4 * 32 + j * 4 + r;
        sfp[al][o] = fmaxf(acc[c4 * 4 + r], 0.f);
      }
    __syncthreads();

    // ---- fused w_t partial product for this temporal slice ----
    const float4* wrow = (const float4*)(w_t + (size_t)tid * TKM + (size_t)ii * MIDC);
    for (int c4 = 0; c4 < MIDC / 4; ++c4) {
      float4 w4 = wrow[c4];
#pragma unroll 8
      for (int a = 0; a < 32; ++a) {
        float4 s4 = *(const float4*)(&sfp[a][c4 * 4]);
        acc2[a] += w4.x * s4.x + w4.y * s4.y + w4.z * s4.z + w4.w * s4.w;
      }
    }
  }

  float* od = out_feat + ((size_t)bt * OUTC + tid) * MP + (size_t)mt * 32;
  float4* od4 = (float4*)od;
#pragma unroll
  for (int q = 0; q < 8; ++q)
    od4[q] = make_float4(acc2[q * 4 + 0], acc2[q * 4 + 1],
                         acc2[q * 4 + 2], acc2[q * 4 + 3]);
}

// ---------------------------------------------------------------------------
extern "C" void kernel_launch(void* const* d_in, const int* in_sizes, int n_in,
                              void* d_out, int out_size, void* d_ws, size_t ws_size,
                              hipStream_t stream) {
  const float* xyzs = (const float*)d_in[0];
  const float* features = (const float*)d_in[1];
  const float* w_d = (const float*)d_in[2];
  const float* w_f = (const float*)d_in[3];
  const float* w_t = (const float*)d_in[4];

  float* out = (float*)d_out;
  float* out_xyz = out;                                        // (B,6,M,3)
  float* out_feat = out + (size_t)BATCH * LFRM * MP * 3;       // (B,6,256,M)
  float* Ft = (float*)d_ws;                                    // (B,L,N,128)

  hipLaunchKernelGGL(fps_ftrans_kernel, dim3(FPS_BLOCKS + FT_BLOCKS), dim3(256),
                     0, stream, xyzs, features, w_f, out_xyz, Ft);
  hipLaunchKernelGGL(pst_main, dim3(BATCH * LFRM * (MP / 32)), dim3(256), 0,
                     stream, xyzs, w_d, w_t, Ft, out_xyz, out_feat);
}

// Round 3
// 1006.812 us; speedup vs baseline: 1.7349x; 1.3126x over previous
//
#include <hip/hip_runtime.h>

#define BATCH 8
#define LFRM  6
#define NP    2048
#define MP    1024
#define CIN   64
#define MIDC  128
#define OUTC  256
#define TKM   384
#define KNN   32
#define RAD2  0.25f

#define FPS_BLOCKS (BATCH * LFRM)
#define FT_BLOCKS  (BATCH * LFRM * (NP / 64))

typedef float f2 __attribute__((ext_vector_type(2)));

// LDS union: fps needs 32KB pts + key slots; ftrans needs 49.25KB.
union SharedU {
  struct {
    float4 pts[NP];                    // 32 KB, [x,y,z,pad]
    unsigned long long wk[2][4];       // parity-double-buffered wave keys
  } fps;
  struct {
    float ftile[CIN][64];              // 16 KB
    float wfT[CIN][MIDC + 1];          // 33 KB
  } ft;
};

// ---- u64 argmax-key helpers: key = (f32_bits(value) << 32) | ~index --------
// max(key) == (max value, min index) == numpy first-occurrence argmax.
__device__ __forceinline__ uint64_t kmax64(uint64_t a, uint64_t b) {
  return a > b ? a : b;
}
template <int CTRL>
__device__ __forceinline__ uint64_t key_dpp(uint64_t k) {
  int lo = __builtin_amdgcn_update_dpp((int)(uint32_t)k, (int)(uint32_t)k,
                                       CTRL, 0xF, 0xF, false);
  int hi = __builtin_amdgcn_update_dpp((int)(uint32_t)(k >> 32),
                                       (int)(uint32_t)(k >> 32),
                                       CTRL, 0xF, 0xF, false);
  return ((uint64_t)(uint32_t)hi << 32) | (uint32_t)lo;
}
__device__ __forceinline__ uint64_t key_swz16(uint64_t k) {
  int lo = __builtin_amdgcn_ds_swizzle((int)(uint32_t)k, 0x401F);  // xor 16
  int hi = __builtin_amdgcn_ds_swizzle((int)(uint32_t)(k >> 32), 0x401F);
  return ((uint64_t)(uint32_t)hi << 32) | (uint32_t)lo;
}
__device__ __forceinline__ uint64_t key_x32(uint64_t k) {
  int lo = __shfl_xor((int)(uint32_t)k, 32);
  int hi = __shfl_xor((int)(uint32_t)(k >> 32), 32);
  return ((uint64_t)(uint32_t)hi << 32) | (uint32_t)lo;
}

// ---------------------------------------------------------------------------
// FPS: 4 waves, 2048 points register-resident (8 pts/lane as 4 f2 pairs).
// One barrier per iteration; wave winners combined via parity-buffered LDS
// key slots. Exact first-occurrence argmax (validated in rounds 1-2).
// ---------------------------------------------------------------------------
__device__ __forceinline__ void fps_path(const float* __restrict__ xyzs,
                                         float* __restrict__ out_xyz,
                                         SharedU* sh) {
#pragma clang fp contract(off)
  const int bt = blockIdx.x;              // b*6 + frame
  const int tid = threadIdx.x;
  const int lane = tid & 63, wv = tid >> 6;
  const float* src = xyzs + (size_t)bt * NP * 3;

  for (int q = tid; q < NP; q += 256)
    sh->fps.pts[q] = make_float4(src[q * 3 + 0], src[q * 3 + 1], src[q * 3 + 2], 0.f);
  __syncthreads();

  // wave wv owns slots [wv*8, wv*8+8); point p = slot*64 + lane
  f2 px[4], py[4], pz[4], dist[4];
#pragma unroll
  for (int u = 0; u < 4; ++u) {
    float4 a = sh->fps.pts[(wv * 8 + 2 * u) * 64 + lane];
    float4 b = sh->fps.pts[(wv * 8 + 2 * u + 1) * 64 + lane];
    px[u] = f2{a.x, b.x};
    py[u] = f2{a.y, b.y};
    pz[u] = f2{a.z, b.z};
    dist[u] = f2{1e10f, 1e10f};
  }

  float4 p0 = sh->fps.pts[0];
  float fx = p0.x, fy = p0.y, fz = p0.z;  // far = 0 initially
  float* dst = out_xyz + (size_t)bt * MP * 3;

  for (int it = 0; it < MP; ++it) {
    if (tid == 0) {                       // emit current far point
      dst[it * 3 + 0] = fx;
      dst[it * 3 + 1] = fy;
      dst[it * 3 + 2] = fz;
    }
    const f2 fx2 = {fx, fx}, fy2 = {fy, fy}, fz2 = {fz, fz};
    float bv = -1.0f;
    int bsu = 0;
#pragma unroll
    for (int u = 0; u < 4; ++u) {
      f2 dx = px[u] - fx2;
      f2 dy = py[u] - fy2;
      f2 dz = pz[u] - fz2;
      f2 m = dx * dx;                     // contract off: ((dx^2+dy^2)+dz^2)
      m = m + dy * dy;
      m = m + dz * dz;
      f2 nd = __builtin_elementwise_min(dist[u], m);
      dist[u] = nd;
      bool cx = nd.x > bv;                // first-occurrence: strict >
      bv = cx ? nd.x : bv;
      bsu = cx ? 2 * u : bsu;
      bool cy = nd.y > bv;
      bv = cy ? nd.y : bv;
      bsu = cy ? 2 * u + 1 : bsu;
    }
    const uint32_t p = (uint32_t)(((wv * 8 + bsu) << 6) | lane);
    uint64_t key = ((uint64_t)__float_as_uint(bv) << 32) | (uint32_t)(~p);
    key = kmax64(key, key_dpp<0x121>(key));   // row_ror:1
    key = kmax64(key, key_dpp<0x122>(key));   // row_ror:2
    key = kmax64(key, key_dpp<0x124>(key));   // row_ror:4
    key = kmax64(key, key_dpp<0x128>(key));   // row_ror:8
    key = kmax64(key, key_swz16(key));        // lane ^ 16
    key = kmax64(key, key_x32(key));          // lane ^ 32

    const int par = it & 1;
    if (lane == 0) sh->fps.wk[par][wv] = key;
    __syncthreads();
    uint64_t k0 = kmax64(sh->fps.wk[par][0], sh->fps.wk[par][1]);
    uint64_t k1 = kmax64(sh->fps.wk[par][2], sh->fps.wk[par][3]);
    uint64_t kg = kmax64(k0, k1);
    const uint32_t wp = ~(uint32_t)kg;        // winner point index
    float4 w = sh->fps.pts[wp];               // uniform -> broadcast read
    fx = w.x; fy = w.y; fz = w.z;
  }
}

// ---------------------------------------------------------------------------
// ftrans: Ft[b,l,n,o] = sum_c w_f[o,c] * features[b,l,c,n]
// ---------------------------------------------------------------------------
__device__ __forceinline__ void ftrans_path(const float* __restrict__ features,
                                            const float* __restrict__ w_f,
                                            float* __restrict__ Ft,
                                            SharedU* sh) {
  const int blk = blockIdx.x - FPS_BLOCKS;
  const int ntile = blk & 31;             // N/64 tiles
  const int bl = blk >> 5;                // b*L + l
  const int tid = threadIdx.x;

  const float* fsrc = features + (size_t)bl * CIN * NP + (size_t)ntile * 64;
  for (int idx = tid; idx < CIN * 64; idx += 256) {
    int c = idx >> 6, n = idx & 63;
    sh->ft.ftile[c][n] = fsrc[(size_t)c * NP + n];
  }
  for (int idx = tid; idx < CIN * MIDC; idx += 256) {
    int c = idx & 63, o = idx >> 6;       // coalesced w_f row reads
    sh->ft.wfT[c][o] = w_f[o * CIN + c];
  }
  __syncthreads();

  const int o = tid & 127, nh = tid >> 7;
  float* dst = Ft + ((size_t)bl * NP + (size_t)ntile * 64) * MIDC;
  for (int q = 0; q < 32; ++q) {
    int n = nh * 32 + q;
    float acc = 0.f;
#pragma unroll 16
    for (int c = 0; c < CIN; ++c) acc += sh->ft.wfT[c][o] * sh->ft.ftile[c][n];
    dst[(size_t)n * MIDC + o] = acc;
  }
}

__global__ __launch_bounds__(256, 1) void fps_ftrans_kernel(
    const float* __restrict__ xyzs, const float* __restrict__ features,
    const float* __restrict__ w_f, float* __restrict__ out_xyz,
    float* __restrict__ Ft) {
  __shared__ SharedU sh;
  if (blockIdx.x < FPS_BLOCKS) {
    fps_path(xyzs, out_xyz, &sh);
    return;
  }
  ftrans_path(features, w_f, Ft, &sh);
}

// ---------------------------------------------------------------------------
// Kernel 3: ball query + max-pool mid + relu + fused w_t GEMM (unchanged).
// ---------------------------------------------------------------------------
__global__ __launch_bounds__(256) void pst_main(const float* __restrict__ xyzs,
                                                const float* __restrict__ w_d,
                                                const float* __restrict__ w_t,
                                                const float* __restrict__ Ft,
                                                const float* __restrict__ anchors,
                                                float* __restrict__ out_feat) {
  __shared__ float pxyz[NP * 3];          // 24 KB frame xyz (interleaved)
  __shared__ float sfp[32][MIDC];         // 16 KB one temporal slice of sf
  __shared__ int nidx[32][KNN];           // 4 KB
  __shared__ float anc[32][3];

  const int blk = blockIdx.x;
  const int mt = blk & 31;                // M/32 tiles
  const int bt = blk >> 5;                // b*6 + (t-1)
  const int b = bt / LFRM;
  const int t = bt % LFRM + 1;            // padded time index, 1..6
  const int tid = threadIdx.x;

  const float* asrc = anchors + ((size_t)bt * MP + (size_t)mt * 32) * 3;
  if (tid < 96) anc[tid / 3][tid % 3] = asrc[tid];
  __syncthreads();

  const int al = tid >> 3;                // anchor 0..31
  const int j = tid & 7;                  // 0..7 within anchor group
  const float ax = anc[al][0], ay = anc[al][1], az = anc[al][2];

  float wd[16][3];
#pragma unroll
  for (int c4 = 0; c4 < 4; ++c4)
#pragma unroll
    for (int r = 0; r < 4; ++r) {
      int o = c4 * 32 + j * 4 + r;
      wd[c4 * 4 + r][0] = w_d[o * 3 + 0];
      wd[c4 * 4 + r][1] = w_d[o * 3 + 1];
      wd[c4 * 4 + r][2] = w_d[o * 3 + 2];
    }

  const int lane = tid & 63, wv = tid >> 6;
  float acc2[32];
#pragma unroll
  for (int a = 0; a < 32; ++a) acc2[a] = 0.f;

  for (int ii = 0; ii < 3; ++ii) {
    const int i = t - 1 + ii;             // padded frame 0..7
    float acc[16];
    __syncthreads();                      // prev slice fully consumed

    if (i == 0 || i == LFRM + 1) {
#pragma unroll
      for (int u = 0; u < 16; ++u)
        acc[u] = -(wd[u][0] * ax + wd[u][1] * ay + wd[u][2] * az);
    } else {
      const int f2i = i - 1;
      const float* fxyz = xyzs + (size_t)(b * LFRM + f2i) * NP * 3;
      for (int q = tid; q < NP * 3; q += 256) pxyz[q] = fxyz[q];
      __syncthreads();

      // ---- ball query: first KNN in-radius indices, in index order ----
      for (int aa = 0; aa < 8; ++aa) {
        const int a = wv * 8 + aa;
        const float qx = anc[a][0], qy = anc[a][1], qz = anc[a][2];
        int total = 0;
        int fillidx = 0;
        for (int ch = 0; ch < NP / 64; ++ch) {
          const int p = ch * 64 + lane;
          float d2;
          {
#pragma clang fp contract(off)
            float dx = qx - pxyz[p * 3 + 0];
            float dy = qy - pxyz[p * 3 + 1];
            float dz = qz - pxyz[p * 3 + 2];
            d2 = dx * dx + dy * dy + dz * dz;
          }
          const bool inb = d2 < RAD2;
          const unsigned long long mk = __ballot(inb);
          if (mk != 0ull && total == 0)
            fillidx = ch * 64 + (int)__builtin_ctzll(mk);
          const int before = (int)__builtin_popcountll(mk & ((1ull << lane) - 1ull));
          const int slot = total + before;
          if (inb && slot < KNN) nidx[a][slot] = p;
          total += (int)__builtin_popcountll(mk);
          if (total >= KNN) break;        // uniform across wave
        }
        const int nf = total < KNN ? total : KNN;
        if (lane < KNN - nf) nidx[a][nf + lane] = fillidx;
      }
      __syncthreads();

      // ---- mid: max over k of (Ft[idx_k] + w_d . disp_k) ----
      const float* ftf = Ft + (size_t)(b * LFRM + f2i) * NP * MIDC;
#pragma unroll
      for (int u = 0; u < 16; ++u) acc[u] = -1e30f;
      for (int k = 0; k < KNN; ++k) {
        const int p = nidx[al][k];
        const float dx = pxyz[p * 3 + 0] - ax;
        const float dy = pxyz[p * 3 + 1] - ay;
        const float dz = pxyz[p * 3 + 2] - az;
        const float4* row = (const float4*)(ftf + (size_t)p * MIDC);
#pragma unroll
        for (int c4 = 0; c4 < 4; ++c4) {
          float4 v = row[c4 * 8 + j];
          const float* vf = (const float*)&v;
#pragma unroll
          for (int r = 0; r < 4; ++r) {
            float dt = wd[c4 * 4 + r][0] * dx + wd[c4 * 4 + r][1] * dy +
                       wd[c4 * 4 + r][2] * dz;
            acc[c4 * 4 + r] = fmaxf(acc[c4 * 4 + r], vf[r] + dt);
          }
        }
      }
    }

    // write relu'd slice to LDS
#pragma unroll
    for (int c4 = 0; c4 < 4; ++c4)
#pragma unroll
      for (int r = 0; r < 4; ++r) {
        int o = c4 * 32 + j * 4 + r;
        sfp[al][o] = fmaxf(acc[c4 * 4 + r], 0.f);
      }
    __syncthreads();

    // ---- fused w_t partial product for this temporal slice ----
    const float4* wrow = (const float4*)(w_t + (size_t)tid * TKM + (size_t)ii * MIDC);
    for (int c4 = 0; c4 < MIDC / 4; ++c4) {
      float4 w4 = wrow[c4];
#pragma unroll 8
      for (int a = 0; a < 32; ++a) {
        float4 s4 = *(const float4*)(&sfp[a][c4 * 4]);
        acc2[a] += w4.x * s4.x + w4.y * s4.y + w4.z * s4.z + w4.w * s4.w;
      }
    }
  }

  float* od = out_feat + ((size_t)bt * OUTC + tid) * MP + (size_t)mt * 32;
  float4* od4 = (float4*)od;
#pragma unroll
  for (int q = 0; q < 8; ++q)
    od4[q] = make_float4(acc2[q * 4 + 0], acc2[q * 4 + 1],
                         acc2[q * 4 + 2], acc2[q * 4 + 3]);
}

// ---------------------------------------------------------------------------
extern "C" void kernel_launch(void* const* d_in, const int* in_sizes, int n_in,
                              void* d_out, int out_size, void* d_ws, size_t ws_size,
                              hipStream_t stream) {
  const float* xyzs = (const float*)d_in[0];
  const float* features = (const float*)d_in[1];
  const float* w_d = (const float*)d_in[2];
  const float* w_f = (const float*)d_in[3];
  const float* w_t = (const float*)d_in[4];

  float* out = (float*)d_out;
  float* out_xyz = out;                                        // (B,6,M,3)
  float* out_feat = out + (size_t)BATCH * LFRM * MP * 3;       // (B,6,256,M)
  float* Ft = (float*)d_ws;                                    // (B,L,N,128)

  hipLaunchKernelGGL(fps_ftrans_kernel, dim3(FPS_BLOCKS + FT_BLOCKS), dim3(256),
                     0, stream, xyzs, features, w_f, out_xyz, Ft);
  hipLaunchKernelGGL(pst_main, dim3(BATCH * LFRM * (MP / 32)), dim3(256), 0,
                     stream, xyzs, w_d, w_t, Ft, out_xyz, out_feat);
}